// Round 5
// baseline (467.524 us; speedup 1.0000x reference)
//
#include <hip/hip_runtime.h>
#include <cstdint>

#define B_SZ 16
#define SEQ 1024
#define DIM 768
#define NH 12
#define HD 64
#define M_TOTAL (B_SZ*SEQ)       // 16384
#define QKV_OUT (3*DIM)          // 2304
#define EXP2_SCALE 0.18033688011f   // (1/8) * log2(e)  -- folded into Q at gemm epilogue

typedef _Float16 f16;
typedef __attribute__((ext_vector_type(8))) f16 f16x8;
typedef __attribute__((ext_vector_type(4))) f16 f16x4;
typedef __attribute__((ext_vector_type(2))) __fp16 pk16x2;   // cvt_pkrtz native type
typedef __attribute__((ext_vector_type(4))) short s4_t;
typedef __attribute__((ext_vector_type(4))) float f32x4;
typedef unsigned int u32;
typedef const __attribute__((address_space(1))) u32* gas_t;
typedef __attribute__((address_space(3))) u32* las_t;

union U4 { pk16x2 h2[2]; f16x4 v; };
union U8 { pk16x2 h2[4]; f16x8 v; };
union HS { f16 h; short s; };

__device__ __forceinline__ void async16(const void* g, void* l) {
    __builtin_amdgcn_global_load_lds((gas_t)g, (las_t)l, 16, 0, 0);
}
__device__ __forceinline__ f32x4 mfma32h(f16x8 a, f16x8 b, f32x4 c) {
    return __builtin_amdgcn_mfma_f32_16x16x32_f16(a, b, c, 0, 0, 0);
}
__device__ __forceinline__ f16x8 ldfragh(const short* p) {
    return *(const f16x8*)p;
}

// ---------------- fp32 -> fp16 conversion of x, w_qkv, w_proj ----------------
__global__ void cvt_kernel(const float* __restrict__ x, const float* __restrict__ wq,
                           const float* __restrict__ wp,
                           short* __restrict__ xb, short* __restrict__ wqb, short* __restrict__ wpb) {
    const long nx = (long)M_TOTAL * DIM / 4;
    const long nq = (long)QKV_OUT * DIM / 4;
    const long np = (long)DIM * DIM / 4;
    const long total = nx + nq + np;
    for (long i = (long)blockIdx.x * blockDim.x + threadIdx.x; i < total;
         i += (long)gridDim.x * blockDim.x) {
        const float4* src; short* dst; long off;
        if (i < nx)            { src = (const float4*)x;  dst = xb;  off = i; }
        else if (i < nx + nq)  { src = (const float4*)wq; dst = wqb; off = i - nx; }
        else                   { src = (const float4*)wp; dst = wpb; off = i - nx - nq; }
        float4 v = src[off];
        U4 u;
        u.h2[0] = __builtin_amdgcn_cvt_pkrtz(v.x, v.y);
        u.h2[1] = __builtin_amdgcn_cvt_pkrtz(v.z, v.w);
        *(f16x4*)(dst + off * 4) = u.v;
    }
}

// one C-quadrant (32 rows x 48 cols per wave) x K=64: 12 MFMA
template<int MH, int NHH>
__device__ __forceinline__ void mfma_quad(f32x4 (&acc)[4][6], const f16x8 (&af)[2][2],
                                          const f16x8 (&bf)[3][2]) {
#pragma unroll
    for (int r = 0; r < 2; ++r)
#pragma unroll
        for (int c = 0; c < 3; ++c) {
            f32x4 t = acc[MH * 2 + r][NHH * 3 + c];
            t = mfma32h(af[r][0], bf[c][0], t);
            t = mfma32h(af[r][1], bf[c][1], t);
            acc[MH * 2 + r][NHH * 3 + c] = t;
        }
}

// ---------------- 256x192-tile 4-phase/tile f16 GEMM:  C = A[M,K] * Bm[N,K]^T -------
// (unchanged from round 4: 78.5 us, 0 bank conflicts, exact 3-round / 1-round packing)
template<int EPI, int N, int K>
__global__ __launch_bounds__(512, 2) void gemm_bt(const short* __restrict__ A,
                                                  const short* __restrict__ Bm,
                                                  short* __restrict__ Cq, short* __restrict__ Ck,
                                                  short* __restrict__ Cv,
                                                  float* __restrict__ Cout,
                                                  const float* __restrict__ bias) {
    static_assert(K % 128 == 0, "even K-tile count required");
    constexpr int NT = K / 64;       // K-tiles (12)
    constexpr int NIT = NT / 2;      // iterations (2 tiles each)
    constexpr int SLOT = 28672;      // shorts per slot: A 256x64 (16384) + B 192x64 (12288)
    __shared__ short lds[2 * SLOT];  // 114688 B

    const int tid = threadIdx.x;
    const int l = tid & 63, quad = l >> 4, l15 = l & 15, l7 = l15 & 7;
    const int w = tid >> 6, wr = w >> 1, wc = w & 1;   // 4M x 2N wave grid

    // bijective XCD swizzle (nwg % 8 == 0 for both instantiations: 768, 256)
    const int gx = gridDim.x;
    const int nwg = gx * (int)gridDim.y;
    int fid = (int)blockIdx.y * gx + (int)blockIdx.x;
    fid = (fid & 7) * (nwg >> 3) + (fid >> 3);
    const int m0 = (fid / gx) * 256;
    const int n0 = (fid % gx) * 192;

    // staging: unit = 512 threads x 1 load = 64 rows x 8 chunks (16B each).
    const int srow = tid >> 3, sc = tid & 7;
    const int scc = sc ^ (srow & 7);            // (row + u*64)&7 == row&7
    const short* Asrc = A + (size_t)(m0 + srow) * K + scc * 8;
    const short* Bsrc = Bm + (size_t)(n0 + srow) * K + scc * 8;
    const int sdst = tid * 8;

#define STAGE_A(t, u) async16(Asrc + (size_t)((u) * 64) * K + (t) * 64, \
                              &lds[((t) & 1) * SLOT + (u) * 4096 + sdst])
#define STAGE_B(t, u) async16(Bsrc + (size_t)((u) * 64) * K + (t) * 64, \
                              &lds[((t) & 1) * SLOT + 16384 + (u) * 4096 + sdst])

    const int awoff = wr * 4096 + l15 * 64;            // A row = wr*64 + MH*32 + r*16 + l15
    const int bwoff = 16384 + wc * 6144 + l15 * 64;    // B row = wc*96 + NH*48 + c*16 + l15
    const int c0 = (quad ^ l7) * 8;
    const int c1 = ((4 + quad) ^ l7) * 8;

#define RD_A(SB, MH) do {                                      \
        const int ab_ = (SB) + awoff + (MH) * 2048;            \
        af[0][0] = ldfragh(&lds[ab_ + c0]);                    \
        af[0][1] = ldfragh(&lds[ab_ + c1]);                    \
        af[1][0] = ldfragh(&lds[ab_ + 1024 + c0]);             \
        af[1][1] = ldfragh(&lds[ab_ + 1024 + c1]);             \
    } while (0)
#define RD_B(SB, NHH) do {                                     \
        const int bb_ = (SB) + bwoff + (NHH) * 3072;           \
        bf[0][0] = ldfragh(&lds[bb_ + c0]);                    \
        bf[0][1] = ldfragh(&lds[bb_ + c1]);                    \
        bf[1][0] = ldfragh(&lds[bb_ + 1024 + c0]);             \
        bf[1][1] = ldfragh(&lds[bb_ + 1024 + c1]);             \
        bf[2][0] = ldfragh(&lds[bb_ + 2048 + c0]);             \
        bf[2][1] = ldfragh(&lds[bb_ + 2048 + c1]);             \
    } while (0)

#define BAR1() __builtin_amdgcn_s_barrier()
#define BAR2() do { __builtin_amdgcn_s_barrier(); __builtin_amdgcn_sched_barrier(0); } while (0)
#define VMC3() asm volatile("s_waitcnt vmcnt(3)" ::: "memory")
#define VMC0() asm volatile("s_waitcnt vmcnt(0)" ::: "memory")
#define MQ(MH, NHH) do {                                       \
        __builtin_amdgcn_s_setprio(1);                         \
        mfma_quad<MH, NHH>(acc, af, bf);                       \
        __builtin_amdgcn_s_setprio(0);                         \
    } while (0)

    f32x4 acc[4][6];
#pragma unroll
    for (int i = 0; i < 4; ++i)
#pragma unroll
        for (int j = 0; j < 6; ++j) acc[i][j] = (f32x4){0.f, 0.f, 0.f, 0.f};
    f16x8 af[2][2], bf[3][2];

    // prologue: B0 (3), A0 (4), B1 (3) = 10 loads; A0+B0 landed, B1 (3) in flight
    STAGE_B(0, 0); STAGE_B(0, 1); STAGE_B(0, 2);
    STAGE_A(0, 0); STAGE_A(0, 1); STAGE_A(0, 2); STAGE_A(0, 3);
    STAGE_B(1, 0); STAGE_B(1, 1); STAGE_B(1, 2);
    VMC3();
    BAR2();

#pragma unroll 1
    for (int i = 0; i < NIT; ++i) {
        const int ta = 2 * i, tb = 2 * i + 1;
        // ---------------- tile ta (slot 0) ----------------
        {
            const int t1 = ta + 1, t2 = ta + 2;
            RD_A(0, 0); RD_B(0, 0);                              // ph1 (mh0,nh0)
            if (t1 < NT) { STAGE_A(t1, 0); STAGE_A(t1, 1); }
            BAR1(); MQ(0, 0); BAR2();

            RD_A(0, 1);                                          // ph2 (mh1,nh0)
            if (t1 < NT) { STAGE_A(t1, 2); STAGE_A(t1, 3); }
            BAR1(); MQ(1, 0); BAR2();

            RD_B(0, 1);                                          // ph3 (mh1,nh1)
            BAR1(); MQ(1, 1); BAR2();

            RD_A(0, 0);                                          // ph4 (mh0,nh1)
            if (t2 < NT) { STAGE_B(t2, 0); STAGE_B(t2, 1); STAGE_B(t2, 2); }
            BAR1(); MQ(0, 1);
            if (t2 < NT) VMC3(); else VMC0();                    // tile ta+1 landed
            BAR2();
        }
        // ---------------- tile tb (slot 1) ----------------
        {
            const int t1 = tb + 1, t2 = tb + 2;
            RD_A(SLOT, 0); RD_B(SLOT, 0);                        // ph5
            if (t1 < NT) { STAGE_A(t1, 0); STAGE_A(t1, 1); }
            BAR1(); MQ(0, 0); BAR2();

            RD_A(SLOT, 1);                                       // ph6
            if (t1 < NT) { STAGE_A(t1, 2); STAGE_A(t1, 3); }
            BAR1(); MQ(1, 0); BAR2();

            RD_B(SLOT, 1);                                       // ph7
            BAR1(); MQ(1, 1); BAR2();

            RD_A(SLOT, 0);                                       // ph8
            if (t2 < NT) { STAGE_B(t2, 0); STAGE_B(t2, 1); STAGE_B(t2, 2); }
            BAR1(); MQ(0, 1);
            if (t2 < NT) VMC3(); else VMC0();                    // tile tb+1 landed
            BAR2();
        }
    }
#undef STAGE_A
#undef STAGE_B
#undef RD_A
#undef RD_B

    // epilogue: acc[rt][ct]: row block (rt>>1)*32 + (rt&1)*16, col block (ct/3)*48 + (ct%3)*16
#pragma unroll
    for (int rt = 0; rt < 4; ++rt) {
        const int mrow = m0 + wr * 64 + (rt >> 1) * 32 + (rt & 1) * 16 + quad * 4;
#pragma unroll
        for (int ct = 0; ct < 6; ++ct) {
            const int col = n0 + wc * 96 + (ct / 3) * 48 + (ct % 3) * 16 + l15;
            if (EPI == 0) {
                int s = col / DIM;
                int h = (col - s * DIM) >> 6, hd = col & 63;
                int b = mrow >> 10, nn = mrow & 1023;
                if (s == 2) {
                    // V transposed: [b][h][hd][n]; 4 consecutive n -> one 8B store
                    U4 u;
                    u.h2[0] = __builtin_amdgcn_cvt_pkrtz(acc[rt][ct][0], acc[rt][ct][1]);
                    u.h2[1] = __builtin_amdgcn_cvt_pkrtz(acc[rt][ct][2], acc[rt][ct][3]);
                    *(f16x4*)&Cv[(((size_t)b * NH + h) * HD + hd) * SEQ + nn] = u.v;
                } else {
                    short* dst = (s == 0) ? Cq : Ck;
                    const float qs = (s == 0) ? EXP2_SCALE : 1.0f;
#pragma unroll
                    for (int r = 0; r < 4; ++r) {
                        HS t; t.h = (f16)(acc[rt][ct][r] * qs);
                        dst[(((size_t)b * NH + h) * SEQ + nn + r) * HD + hd] = t.s;
                    }
                }
            } else {
                float bv = bias[col];
#pragma unroll
                for (int r = 0; r < 4; ++r)
                    Cout[(size_t)(mrow + r) * N + col] = acc[rt][ct][r] + bv;
            }
        }
    }
}

// ---------------- attention: LDS-staged flash, KVBLK=64, 3-buffer pipeline ----------
// 64 q-rows per wave (256/block, 768 blocks = 3/CU all resident; launch_bounds(256,3)
// pins VGPR<=170 so occupancy can't drop). KV-block 64 rows per phase (16 phases, was
// 32): HALVES the vmcnt+barrier sync events, and the two independent 32-kv halves in
// one phase give cross-half ILP -- half1's ds_read+QK overlap half0's exp/cvt/PV
// chain with no barrier between. 3 buffers x 16 KB (K 64x64 | V^T 64x64), 2-stage
// prefetch (8 loads in flight), vmcnt(4) steady. Swizzles identical to the proven
// 32-row/32-col patterns, applied per half (rule 21 both-sides).
__global__ __launch_bounds__(256, 3) void attn_kernel(const short* __restrict__ Q,
                                                      const short* __restrict__ Km,
                                                      const short* __restrict__ Vt,
                                                      short* __restrict__ O) {
    __shared__ short lds[3][8192];   // per buffer: K[2 half][32x64] | V^T[2 half][64x32]
    const int tid = threadIdx.x;
    const int w = tid >> 6, l = tid & 63, quad = l >> 4, l15 = l & 15;
    const int bid = blockIdx.x;
    const int xcd = bid & 7, kk = bid >> 3;
    const int head = xcd + 8 * (kk >> 2);        // 0..191, 4 q-chunks/head per XCD
    const int q0 = (kk & 3) * 256 + w * 64;      // this wave's 64 q rows
    const int b = head / NH, h = head - b * NH;
    const short* Qp = Q + (size_t)head * (SEQ * HD);
    const short* Kp = Km + (size_t)head * (SEQ * HD);
    const short* Vp = Vt + (size_t)head * (SEQ * HD);   // [hd][n]

    // Q as B-operand fragments: B[n=q=l15][k=hd=quad*8+j]; EXP2_SCALE pre-folded.
    f16x8 qf[4][2];
#pragma unroll
    for (int qt = 0; qt < 4; ++qt)
#pragma unroll
        for (int hf = 0; hf < 2; ++hf)
            qf[qt][hf] = *(const f16x8*)&Qp[(q0 + qt * 16 + l15) * HD + hf * 32 + quad * 8];

    f32x4 oacc[4][4];
#pragma unroll
    for (int qt = 0; qt < 4; ++qt)
#pragma unroll
        for (int ht = 0; ht < 4; ++ht) oacc[qt][ht] = (f32x4){0.f, 0.f, 0.f, 0.f};
    float psum[4] = {0.f, 0.f, 0.f, 0.f};

    // staging: 4 x 16B per thread per 64-kv block (2 K-halves + 2 V-halves)
    const int kr = tid >> 3, kc = tid & 7;
    const int kcc = kc ^ ((kr & 3) ^ (((kr >> 3) & 3) << 1));
    const short* kSrc = Kp + kr * HD + kcc * 8;     // + (g*64 + u*32)*HD per block
    const int kDst = kr * 64 + kc * 8;              // + u*2048
    const int vr = tid >> 2, vc = tid & 3;
    const int vcc = vc ^ ((vr >> 1) & 3);
    const short* vSrc = Vp + vr * SEQ + vcc * 8;    // + g*64 + hf*32 per block
    const int vDst = 4096 + vr * 32 + vc * 8;       // + hf*2048

#define STAGE(bf, g) do {                                            \
        async16(kSrc + (size_t)(g) * 64 * HD, &lds[bf][kDst]);       \
        async16(kSrc + (size_t)((g) * 64 + 32) * HD,                 \
                &lds[bf][kDst + 2048]);                              \
        async16(vSrc + (g) * 64, &lds[bf][vDst]);                    \
        async16(vSrc + (g) * 64 + 32, &lds[bf][vDst + 2048]);        \
    } while (0)

    const int rA = 8 * (l15 >> 2) + (l15 & 3);
    const int sk = (l15 & 3) ^ ((l15 >> 2) << 1);
    const int offK = rA * 64 + ((quad ^ sk) * 8);                        // + half*2048
    const int offV = 4096 + l15 * 32 + ((quad ^ ((l15 >> 1) & 3)) * 8);  // + half*2048

    STAGE(0, 0); STAGE(1, 1);   // 2-deep prologue (8 loads in flight)

    int cur = 0, nb = 2;        // cur = g%3, nb = (g+2)%3, tracked incrementally
    for (int g = 0; g < 16; ++g) {
        if (g <= 14) asm volatile("s_waitcnt vmcnt(4)" ::: "memory");
        else         asm volatile("s_waitcnt vmcnt(0)" ::: "memory");
        __builtin_amdgcn_s_barrier();
        // buf nb was last read at iter g-1; all waves crossed the barrier after
        // consuming their ds_reads of it -> safe to overwrite.
        if (g < 14) STAGE(nb, g + 2);

        const short* bufp = &lds[cur][0];
#pragma unroll
        for (int half = 0; half < 2; ++half) {
            const short* kb = bufp + half * 2048;
            f16x8 kA0 = ldfragh(kb + offK);
            f16x8 kA1 = ldfragh(kb + (offK ^ 32));
            f16x8 kB0 = ldfragh(kb + offK + 256);
            f16x8 kB1 = ldfragh(kb + (offK ^ 32) + 256);
            f16x8 v0 = ldfragh(kb + offV);
            f16x8 v1 = ldfragh(kb + offV + 512);
            f16x8 v2 = ldfragh(kb + offV + 1024);
            f16x8 v3 = ldfragh(kb + offV + 1536);

            __builtin_amdgcn_s_setprio(1);
#pragma unroll
            for (int qt = 0; qt < 4; ++qt) {
                f32x4 sA = (f32x4){0.f, 0.f, 0.f, 0.f};
                sA = mfma32h(kA0, qf[qt][0], sA);
                sA = mfma32h(kA1, qf[qt][1], sA);
                f32x4 sB = (f32x4){0.f, 0.f, 0.f, 0.f};
                sB = mfma32h(kB0, qf[qt][0], sB);
                sB = mfma32h(kB1, qf[qt][1], sB);
                float eA0 = __builtin_amdgcn_exp2f(sA[0]);
                float eA1 = __builtin_amdgcn_exp2f(sA[1]);
                float eA2 = __builtin_amdgcn_exp2f(sA[2]);
                float eA3 = __builtin_amdgcn_exp2f(sA[3]);
                float eB0 = __builtin_amdgcn_exp2f(sB[0]);
                float eB1 = __builtin_amdgcn_exp2f(sB[1]);
                float eB2 = __builtin_amdgcn_exp2f(sB[2]);
                float eB3 = __builtin_amdgcn_exp2f(sB[3]);
                psum[qt] += ((eA0 + eA1) + (eA2 + eA3)) + ((eB0 + eB1) + (eB2 + eB3));
                U8 u;
                u.h2[0] = __builtin_amdgcn_cvt_pkrtz(eA0, eA1);
                u.h2[1] = __builtin_amdgcn_cvt_pkrtz(eA2, eA3);
                u.h2[2] = __builtin_amdgcn_cvt_pkrtz(eB0, eB1);
                u.h2[3] = __builtin_amdgcn_cvt_pkrtz(eB2, eB3);
                oacc[qt][0] = mfma32h(v0, u.v, oacc[qt][0]);
                oacc[qt][1] = mfma32h(v1, u.v, oacc[qt][1]);
                oacc[qt][2] = mfma32h(v2, u.v, oacc[qt][2]);
                oacc[qt][3] = mfma32h(v3, u.v, oacc[qt][3]);
            }
            __builtin_amdgcn_s_setprio(0);
        }
        cur = (cur == 2) ? 0 : cur + 1;
        nb = (nb == 2) ? 0 : nb + 1;
    }
#undef STAGE

    // full row sums: reduce partials across the 4 quads (lanes differing in bits 4,5)
#pragma unroll
    for (int qt = 0; qt < 4; ++qt) {
        psum[qt] += __shfl_xor(psum[qt], 16);
        psum[qt] += __shfl_xor(psum[qt], 32);
    }

    // epilogue: lane holds O[q=l15][hd=ht*16+quad*4+r] -> four 8B stores per q-tile
#pragma unroll
    for (int qt = 0; qt < 4; ++qt) {
        float rinv = 1.0f / psum[qt];
        short* orow = &O[((size_t)b * SEQ + q0 + qt * 16 + l15) * DIM + h * HD + quad * 4];
#pragma unroll
        for (int ht = 0; ht < 4; ++ht) {
            U4 u;
            u.h2[0] = __builtin_amdgcn_cvt_pkrtz(oacc[qt][ht][0] * rinv, oacc[qt][ht][1] * rinv);
            u.h2[1] = __builtin_amdgcn_cvt_pkrtz(oacc[qt][ht][2] * rinv, oacc[qt][ht][3] * rinv);
            *(f16x4*)(orow + ht * 16) = u.v;
        }
    }
}

extern "C" void kernel_launch(void* const* d_in, const int* in_sizes, int n_in,
                              void* d_out, int out_size, void* d_ws, size_t ws_size,
                              hipStream_t stream) {
    const float* x      = (const float*)d_in[0];
    const float* w_qkv  = (const float*)d_in[1];
    const float* w_proj = (const float*)d_in[2];
    const float* b_proj = (const float*)d_in[3];
    float* out = (float*)d_out;

    short* p = (short*)d_ws;
    short* Xb  = p; p += (size_t)M_TOTAL * DIM;
    short* Wqb = p; p += (size_t)QKV_OUT * DIM;
    short* Wpb = p; p += (size_t)DIM * DIM;
    short* Qb  = p; p += (size_t)B_SZ * NH * SEQ * HD;
    short* Kb  = p; p += (size_t)B_SZ * NH * SEQ * HD;
    short* Vtb = p; p += (size_t)B_SZ * NH * SEQ * HD;   // transposed [b][h][hd][n]
    short* Ob  = p; p += (size_t)M_TOTAL * DIM;

    cvt_kernel<<<1024, 256, 0, stream>>>(x, w_qkv, w_proj, Xb, Wqb, Wpb);
    gemm_bt<0, QKV_OUT, DIM><<<dim3(QKV_OUT / 192, M_TOTAL / 256), 512, 0, stream>>>(
        Xb, Wqb, Qb, Kb, Vtb, nullptr, nullptr);
    attn_kernel<<<B_SZ * NH * (SEQ / 256), 256, 0, stream>>>(Qb, Kb, Vtb, Ob);
    gemm_bt<1, DIM, DIM><<<dim3(DIM / 192, M_TOTAL / 256), 512, 0, stream>>>(
        Ob, Wpb, nullptr, nullptr, nullptr, out, b_proj);
}

// Round 6
// 275.300 us; speedup vs baseline: 1.6982x; 1.6982x over previous
//
#include <hip/hip_runtime.h>
#include <cstdint>

#define B_SZ 16
#define SEQ 1024
#define DIM 768
#define NH 12
#define HD 64
#define M_TOTAL (B_SZ*SEQ)       // 16384
#define QKV_OUT (3*DIM)          // 2304
#define EXP2_SCALE 0.18033688011f   // (1/8) * log2(e)  -- folded into Q at gemm epilogue

typedef _Float16 f16;
typedef __attribute__((ext_vector_type(8))) f16 f16x8;
typedef __attribute__((ext_vector_type(4))) f16 f16x4;
typedef __attribute__((ext_vector_type(2))) __fp16 pk16x2;   // cvt_pkrtz native type
typedef __attribute__((ext_vector_type(4))) short s4_t;
typedef __attribute__((ext_vector_type(4))) float f32x4;
typedef unsigned int u32;
typedef const __attribute__((address_space(1))) u32* gas_t;
typedef __attribute__((address_space(3))) u32* las_t;

union U4 { pk16x2 h2[2]; f16x4 v; };
union U8 { pk16x2 h2[4]; f16x8 v; };
union HS { f16 h; short s; };

__device__ __forceinline__ void async16(const void* g, void* l) {
    __builtin_amdgcn_global_load_lds((gas_t)g, (las_t)l, 16, 0, 0);
}
__device__ __forceinline__ f32x4 mfma32h(f16x8 a, f16x8 b, f32x4 c) {
    return __builtin_amdgcn_mfma_f32_16x16x32_f16(a, b, c, 0, 0, 0);
}
__device__ __forceinline__ f16x8 ldfragh(const short* p) {
    return *(const f16x8*)p;
}

// ---------------- fp32 -> fp16 conversion of x, w_qkv, w_proj ----------------
__global__ void cvt_kernel(const float* __restrict__ x, const float* __restrict__ wq,
                           const float* __restrict__ wp,
                           short* __restrict__ xb, short* __restrict__ wqb, short* __restrict__ wpb) {
    const long nx = (long)M_TOTAL * DIM / 4;
    const long nq = (long)QKV_OUT * DIM / 4;
    const long np = (long)DIM * DIM / 4;
    const long total = nx + nq + np;
    for (long i = (long)blockIdx.x * blockDim.x + threadIdx.x; i < total;
         i += (long)gridDim.x * blockDim.x) {
        const float4* src; short* dst; long off;
        if (i < nx)            { src = (const float4*)x;  dst = xb;  off = i; }
        else if (i < nx + nq)  { src = (const float4*)wq; dst = wqb; off = i - nx; }
        else                   { src = (const float4*)wp; dst = wpb; off = i - nx - nq; }
        float4 v = src[off];
        U4 u;
        u.h2[0] = __builtin_amdgcn_cvt_pkrtz(v.x, v.y);
        u.h2[1] = __builtin_amdgcn_cvt_pkrtz(v.z, v.w);
        *(f16x4*)(dst + off * 4) = u.v;
    }
}

// one C-quadrant (32 rows x 48 cols per wave) x K=64: 12 MFMA
template<int MH, int NHH>
__device__ __forceinline__ void mfma_quad(f32x4 (&acc)[4][6], const f16x8 (&af)[2][2],
                                          const f16x8 (&bf)[3][2]) {
#pragma unroll
    for (int r = 0; r < 2; ++r)
#pragma unroll
        for (int c = 0; c < 3; ++c) {
            f32x4 t = acc[MH * 2 + r][NHH * 3 + c];
            t = mfma32h(af[r][0], bf[c][0], t);
            t = mfma32h(af[r][1], bf[c][1], t);
            acc[MH * 2 + r][NHH * 3 + c] = t;
        }
}

// ---------------- 256x192-tile 4-phase/tile f16 GEMM:  C = A[M,K] * Bm[N,K]^T -------
// (unchanged from round 4: 78.5 us, 0 bank conflicts, exact 3-round / 1-round packing)
template<int EPI, int N, int K>
__global__ __launch_bounds__(512, 2) void gemm_bt(const short* __restrict__ A,
                                                  const short* __restrict__ Bm,
                                                  short* __restrict__ Cq, short* __restrict__ Ck,
                                                  short* __restrict__ Cv,
                                                  float* __restrict__ Cout,
                                                  const float* __restrict__ bias) {
    static_assert(K % 128 == 0, "even K-tile count required");
    constexpr int NT = K / 64;       // K-tiles (12)
    constexpr int NIT = NT / 2;      // iterations (2 tiles each)
    constexpr int SLOT = 28672;      // shorts per slot: A 256x64 (16384) + B 192x64 (12288)
    __shared__ short lds[2 * SLOT];  // 114688 B

    const int tid = threadIdx.x;
    const int l = tid & 63, quad = l >> 4, l15 = l & 15, l7 = l15 & 7;
    const int w = tid >> 6, wr = w >> 1, wc = w & 1;   // 4M x 2N wave grid

    // bijective XCD swizzle (nwg % 8 == 0 for both instantiations: 768, 256)
    const int gx = gridDim.x;
    const int nwg = gx * (int)gridDim.y;
    int fid = (int)blockIdx.y * gx + (int)blockIdx.x;
    fid = (fid & 7) * (nwg >> 3) + (fid >> 3);
    const int m0 = (fid / gx) * 256;
    const int n0 = (fid % gx) * 192;

    // staging: unit = 512 threads x 1 load = 64 rows x 8 chunks (16B each).
    const int srow = tid >> 3, sc = tid & 7;
    const int scc = sc ^ (srow & 7);            // (row + u*64)&7 == row&7
    const short* Asrc = A + (size_t)(m0 + srow) * K + scc * 8;
    const short* Bsrc = Bm + (size_t)(n0 + srow) * K + scc * 8;
    const int sdst = tid * 8;

#define STAGE_A(t, u) async16(Asrc + (size_t)((u) * 64) * K + (t) * 64, \
                              &lds[((t) & 1) * SLOT + (u) * 4096 + sdst])
#define STAGE_B(t, u) async16(Bsrc + (size_t)((u) * 64) * K + (t) * 64, \
                              &lds[((t) & 1) * SLOT + 16384 + (u) * 4096 + sdst])

    const int awoff = wr * 4096 + l15 * 64;            // A row = wr*64 + MH*32 + r*16 + l15
    const int bwoff = 16384 + wc * 6144 + l15 * 64;    // B row = wc*96 + NH*48 + c*16 + l15
    const int c0 = (quad ^ l7) * 8;
    const int c1 = ((4 + quad) ^ l7) * 8;

#define RD_A(SB, MH) do {                                      \
        const int ab_ = (SB) + awoff + (MH) * 2048;            \
        af[0][0] = ldfragh(&lds[ab_ + c0]);                    \
        af[0][1] = ldfragh(&lds[ab_ + c1]);                    \
        af[1][0] = ldfragh(&lds[ab_ + 1024 + c0]);             \
        af[1][1] = ldfragh(&lds[ab_ + 1024 + c1]);             \
    } while (0)
#define RD_B(SB, NHH) do {                                     \
        const int bb_ = (SB) + bwoff + (NHH) * 3072;           \
        bf[0][0] = ldfragh(&lds[bb_ + c0]);                    \
        bf[0][1] = ldfragh(&lds[bb_ + c1]);                    \
        bf[1][0] = ldfragh(&lds[bb_ + 1024 + c0]);             \
        bf[1][1] = ldfragh(&lds[bb_ + 1024 + c1]);             \
        bf[2][0] = ldfragh(&lds[bb_ + 2048 + c0]);             \
        bf[2][1] = ldfragh(&lds[bb_ + 2048 + c1]);             \
    } while (0)

#define BAR1() __builtin_amdgcn_s_barrier()
#define BAR2() do { __builtin_amdgcn_s_barrier(); __builtin_amdgcn_sched_barrier(0); } while (0)
#define VMC3() asm volatile("s_waitcnt vmcnt(3)" ::: "memory")
#define VMC0() asm volatile("s_waitcnt vmcnt(0)" ::: "memory")
#define MQ(MH, NHH) do {                                       \
        __builtin_amdgcn_s_setprio(1);                         \
        mfma_quad<MH, NHH>(acc, af, bf);                       \
        __builtin_amdgcn_s_setprio(0);                         \
    } while (0)

    f32x4 acc[4][6];
#pragma unroll
    for (int i = 0; i < 4; ++i)
#pragma unroll
        for (int j = 0; j < 6; ++j) acc[i][j] = (f32x4){0.f, 0.f, 0.f, 0.f};
    f16x8 af[2][2], bf[3][2];

    // prologue: B0 (3), A0 (4), B1 (3) = 10 loads; A0+B0 landed, B1 (3) in flight
    STAGE_B(0, 0); STAGE_B(0, 1); STAGE_B(0, 2);
    STAGE_A(0, 0); STAGE_A(0, 1); STAGE_A(0, 2); STAGE_A(0, 3);
    STAGE_B(1, 0); STAGE_B(1, 1); STAGE_B(1, 2);
    VMC3();
    BAR2();

#pragma unroll 1
    for (int i = 0; i < NIT; ++i) {
        const int ta = 2 * i, tb = 2 * i + 1;
        // ---------------- tile ta (slot 0) ----------------
        {
            const int t1 = ta + 1, t2 = ta + 2;
            RD_A(0, 0); RD_B(0, 0);                              // ph1 (mh0,nh0)
            if (t1 < NT) { STAGE_A(t1, 0); STAGE_A(t1, 1); }
            BAR1(); MQ(0, 0); BAR2();

            RD_A(0, 1);                                          // ph2 (mh1,nh0)
            if (t1 < NT) { STAGE_A(t1, 2); STAGE_A(t1, 3); }
            BAR1(); MQ(1, 0); BAR2();

            RD_B(0, 1);                                          // ph3 (mh1,nh1)
            BAR1(); MQ(1, 1); BAR2();

            RD_A(0, 0);                                          // ph4 (mh0,nh1)
            if (t2 < NT) { STAGE_B(t2, 0); STAGE_B(t2, 1); STAGE_B(t2, 2); }
            BAR1(); MQ(0, 1);
            if (t2 < NT) VMC3(); else VMC0();                    // tile ta+1 landed
            BAR2();
        }
        // ---------------- tile tb (slot 1) ----------------
        {
            const int t1 = tb + 1, t2 = tb + 2;
            RD_A(SLOT, 0); RD_B(SLOT, 0);                        // ph5
            if (t1 < NT) { STAGE_A(t1, 0); STAGE_A(t1, 1); }
            BAR1(); MQ(0, 0); BAR2();

            RD_A(SLOT, 1);                                       // ph6
            if (t1 < NT) { STAGE_A(t1, 2); STAGE_A(t1, 3); }
            BAR1(); MQ(1, 0); BAR2();

            RD_B(SLOT, 1);                                       // ph7
            BAR1(); MQ(1, 1); BAR2();

            RD_A(SLOT, 0);                                       // ph8
            if (t2 < NT) { STAGE_B(t2, 0); STAGE_B(t2, 1); STAGE_B(t2, 2); }
            BAR1(); MQ(0, 1);
            if (t2 < NT) VMC3(); else VMC0();                    // tile tb+1 landed
            BAR2();
        }
    }
#undef STAGE_A
#undef STAGE_B
#undef RD_A
#undef RD_B

    // epilogue: acc[rt][ct]: row block (rt>>1)*32 + (rt&1)*16, col block (ct/3)*48 + (ct%3)*16
#pragma unroll
    for (int rt = 0; rt < 4; ++rt) {
        const int mrow = m0 + wr * 64 + (rt >> 1) * 32 + (rt & 1) * 16 + quad * 4;
#pragma unroll
        for (int ct = 0; ct < 6; ++ct) {
            const int col = n0 + wc * 96 + (ct / 3) * 48 + (ct % 3) * 16 + l15;
            if (EPI == 0) {
                int s = col / DIM;
                int h = (col - s * DIM) >> 6, hd = col & 63;
                int b = mrow >> 10, nn = mrow & 1023;
                if (s == 2) {
                    // V transposed: [b][h][hd][n]; 4 consecutive n -> one 8B store
                    U4 u;
                    u.h2[0] = __builtin_amdgcn_cvt_pkrtz(acc[rt][ct][0], acc[rt][ct][1]);
                    u.h2[1] = __builtin_amdgcn_cvt_pkrtz(acc[rt][ct][2], acc[rt][ct][3]);
                    *(f16x4*)&Cv[(((size_t)b * NH + h) * HD + hd) * SEQ + nn] = u.v;
                } else {
                    short* dst = (s == 0) ? Cq : Ck;
                    const float qs = (s == 0) ? EXP2_SCALE : 1.0f;
#pragma unroll
                    for (int r = 0; r < 4; ++r) {
                        HS t; t.h = (f16)(acc[rt][ct][r] * qs);
                        dst[(((size_t)b * NH + h) * SEQ + nn + r) * HD + hd] = t.s;
                    }
                }
            } else {
                float bv = bias[col];
#pragma unroll
                for (int r = 0; r < 4; ++r)
                    Cout[(size_t)(mrow + r) * N + col] = acc[rt][ct][r] + bv;
            }
        }
    }
}

// ---------------- attention: LDS-staged flash, KVBLK=64, 3-buffer pipeline ----------
// Same structure as round 5 but with PLAIN __launch_bounds__(256): R5's (256,3) made
// the compiler clamp arch VGPRs to 84 (cap ~ 256/arg on this toolchain) while the
// kernel needs ~96-110 arch regs -> per-iteration scratch spill = 1.1 GB/dispatch HBM
// traffic = the entire 3x regression. No cap -> no spill; occupancy settles at 2-3
// blocks/CU naturally (48 KB LDS, ~170 total regs).
__global__ __launch_bounds__(256) void attn_kernel(const short* __restrict__ Q,
                                                   const short* __restrict__ Km,
                                                   const short* __restrict__ Vt,
                                                   short* __restrict__ O) {
    __shared__ short lds[3][8192];   // per buffer: K[2 half][32x64] | V^T[2 half][64x32]
    const int tid = threadIdx.x;
    const int w = tid >> 6, l = tid & 63, quad = l >> 4, l15 = l & 15;
    const int bid = blockIdx.x;
    const int xcd = bid & 7, kk = bid >> 3;
    const int head = xcd + 8 * (kk >> 2);        // 0..191, 4 q-chunks/head per XCD
    const int q0 = (kk & 3) * 256 + w * 64;      // this wave's 64 q rows
    const int b = head / NH, h = head - b * NH;
    const short* Qp = Q + (size_t)head * (SEQ * HD);
    const short* Kp = Km + (size_t)head * (SEQ * HD);
    const short* Vp = Vt + (size_t)head * (SEQ * HD);   // [hd][n]

    // Q as B-operand fragments: B[n=q=l15][k=hd=quad*8+j]; EXP2_SCALE pre-folded.
    f16x8 qf[4][2];
#pragma unroll
    for (int qt = 0; qt < 4; ++qt)
#pragma unroll
        for (int hf = 0; hf < 2; ++hf)
            qf[qt][hf] = *(const f16x8*)&Qp[(q0 + qt * 16 + l15) * HD + hf * 32 + quad * 8];

    f32x4 oacc[4][4];
#pragma unroll
    for (int qt = 0; qt < 4; ++qt)
#pragma unroll
        for (int ht = 0; ht < 4; ++ht) oacc[qt][ht] = (f32x4){0.f, 0.f, 0.f, 0.f};
    float psum[4] = {0.f, 0.f, 0.f, 0.f};

    // staging: 4 x 16B per thread per 64-kv block (2 K-halves + 2 V-halves)
    const int kr = tid >> 3, kc = tid & 7;
    const int kcc = kc ^ ((kr & 3) ^ (((kr >> 3) & 3) << 1));
    const short* kSrc = Kp + kr * HD + kcc * 8;     // + (g*64 + u*32)*HD per block
    const int kDst = kr * 64 + kc * 8;              // + u*2048
    const int vr = tid >> 2, vc = tid & 3;
    const int vcc = vc ^ ((vr >> 1) & 3);
    const short* vSrc = Vp + vr * SEQ + vcc * 8;    // + g*64 + hf*32 per block
    const int vDst = 4096 + vr * 32 + vc * 8;       // + hf*2048

#define STAGE(bf, g) do {                                            \
        async16(kSrc + (size_t)(g) * 64 * HD, &lds[bf][kDst]);       \
        async16(kSrc + (size_t)((g) * 64 + 32) * HD,                 \
                &lds[bf][kDst + 2048]);                              \
        async16(vSrc + (g) * 64, &lds[bf][vDst]);                    \
        async16(vSrc + (g) * 64 + 32, &lds[bf][vDst + 2048]);        \
    } while (0)

    const int rA = 8 * (l15 >> 2) + (l15 & 3);
    const int sk = (l15 & 3) ^ ((l15 >> 2) << 1);
    const int offK = rA * 64 + ((quad ^ sk) * 8);                        // + half*2048
    const int offV = 4096 + l15 * 32 + ((quad ^ ((l15 >> 1) & 3)) * 8);  // + half*2048

    STAGE(0, 0); STAGE(1, 1);   // 2-deep prologue (8 loads in flight)

    int cur = 0, nb = 2;        // cur = g%3, nb = (g+2)%3, tracked incrementally
    for (int g = 0; g < 16; ++g) {
        if (g <= 14) asm volatile("s_waitcnt vmcnt(4)" ::: "memory");
        else         asm volatile("s_waitcnt vmcnt(0)" ::: "memory");
        __builtin_amdgcn_s_barrier();
        // buf nb was last read at iter g-1; all waves crossed the barrier after
        // consuming their ds_reads of it -> safe to overwrite.
        if (g < 14) STAGE(nb, g + 2);

        const short* bufp = &lds[cur][0];
#pragma unroll
        for (int half = 0; half < 2; ++half) {
            const short* kb = bufp + half * 2048;
            f16x8 kA0 = ldfragh(kb + offK);
            f16x8 kA1 = ldfragh(kb + (offK ^ 32));
            f16x8 kB0 = ldfragh(kb + offK + 256);
            f16x8 kB1 = ldfragh(kb + (offK ^ 32) + 256);
            f16x8 v0 = ldfragh(kb + offV);
            f16x8 v1 = ldfragh(kb + offV + 512);
            f16x8 v2 = ldfragh(kb + offV + 1024);
            f16x8 v3 = ldfragh(kb + offV + 1536);

            __builtin_amdgcn_s_setprio(1);
#pragma unroll
            for (int qt = 0; qt < 4; ++qt) {
                f32x4 sA = (f32x4){0.f, 0.f, 0.f, 0.f};
                sA = mfma32h(kA0, qf[qt][0], sA);
                sA = mfma32h(kA1, qf[qt][1], sA);
                f32x4 sB = (f32x4){0.f, 0.f, 0.f, 0.f};
                sB = mfma32h(kB0, qf[qt][0], sB);
                sB = mfma32h(kB1, qf[qt][1], sB);
                float eA0 = __builtin_amdgcn_exp2f(sA[0]);
                float eA1 = __builtin_amdgcn_exp2f(sA[1]);
                float eA2 = __builtin_amdgcn_exp2f(sA[2]);
                float eA3 = __builtin_amdgcn_exp2f(sA[3]);
                float eB0 = __builtin_amdgcn_exp2f(sB[0]);
                float eB1 = __builtin_amdgcn_exp2f(sB[1]);
                float eB2 = __builtin_amdgcn_exp2f(sB[2]);
                float eB3 = __builtin_amdgcn_exp2f(sB[3]);
                psum[qt] += ((eA0 + eA1) + (eA2 + eA3)) + ((eB0 + eB1) + (eB2 + eB3));
                U8 u;
                u.h2[0] = __builtin_amdgcn_cvt_pkrtz(eA0, eA1);
                u.h2[1] = __builtin_amdgcn_cvt_pkrtz(eA2, eA3);
                u.h2[2] = __builtin_amdgcn_cvt_pkrtz(eB0, eB1);
                u.h2[3] = __builtin_amdgcn_cvt_pkrtz(eB2, eB3);
                oacc[qt][0] = mfma32h(v0, u.v, oacc[qt][0]);
                oacc[qt][1] = mfma32h(v1, u.v, oacc[qt][1]);
                oacc[qt][2] = mfma32h(v2, u.v, oacc[qt][2]);
                oacc[qt][3] = mfma32h(v3, u.v, oacc[qt][3]);
            }
            __builtin_amdgcn_s_setprio(0);
        }
        cur = (cur == 2) ? 0 : cur + 1;
        nb = (nb == 2) ? 0 : nb + 1;
    }
#undef STAGE

    // full row sums: reduce partials across the 4 quads (lanes differing in bits 4,5)
#pragma unroll
    for (int qt = 0; qt < 4; ++qt) {
        psum[qt] += __shfl_xor(psum[qt], 16);
        psum[qt] += __shfl_xor(psum[qt], 32);
    }

    // epilogue: lane holds O[q=l15][hd=ht*16+quad*4+r] -> four 8B stores per q-tile
#pragma unroll
    for (int qt = 0; qt < 4; ++qt) {
        float rinv = 1.0f / psum[qt];
        short* orow = &O[((size_t)b * SEQ + q0 + qt * 16 + l15) * DIM + h * HD + quad * 4];
#pragma unroll
        for (int ht = 0; ht < 4; ++ht) {
            U4 u;
            u.h2[0] = __builtin_amdgcn_cvt_pkrtz(oacc[qt][ht][0] * rinv, oacc[qt][ht][1] * rinv);
            u.h2[1] = __builtin_amdgcn_cvt_pkrtz(oacc[qt][ht][2] * rinv, oacc[qt][ht][3] * rinv);
            *(f16x4*)(orow + ht * 16) = u.v;
        }
    }
}

extern "C" void kernel_launch(void* const* d_in, const int* in_sizes, int n_in,
                              void* d_out, int out_size, void* d_ws, size_t ws_size,
                              hipStream_t stream) {
    const float* x      = (const float*)d_in[0];
    const float* w_qkv  = (const float*)d_in[1];
    const float* w_proj = (const float*)d_in[2];
    const float* b_proj = (const float*)d_in[3];
    float* out = (float*)d_out;

    short* p = (short*)d_ws;
    short* Xb  = p; p += (size_t)M_TOTAL * DIM;
    short* Wqb = p; p += (size_t)QKV_OUT * DIM;
    short* Wpb = p; p += (size_t)DIM * DIM;
    short* Qb  = p; p += (size_t)B_SZ * NH * SEQ * HD;
    short* Kb  = p; p += (size_t)B_SZ * NH * SEQ * HD;
    short* Vtb = p; p += (size_t)B_SZ * NH * SEQ * HD;   // transposed [b][h][hd][n]
    short* Ob  = p; p += (size_t)M_TOTAL * DIM;

    cvt_kernel<<<1024, 256, 0, stream>>>(x, w_qkv, w_proj, Xb, Wqb, Wpb);
    gemm_bt<0, QKV_OUT, DIM><<<dim3(QKV_OUT / 192, M_TOTAL / 256), 512, 0, stream>>>(
        Xb, Wqb, Qb, Kb, Vtb, nullptr, nullptr);
    attn_kernel<<<B_SZ * NH * (SEQ / 256), 256, 0, stream>>>(Qb, Kb, Vtb, Ob);
    gemm_bt<1, DIM, DIM><<<dim3(DIM / 192, M_TOTAL / 256), 512, 0, stream>>>(
        Ob, Wpb, nullptr, nullptr, nullptr, out, b_proj);
}

// Round 7
// 264.882 us; speedup vs baseline: 1.7650x; 1.0393x over previous
//
#include <hip/hip_runtime.h>
#include <cstdint>

#define B_SZ 16
#define SEQ 1024
#define DIM 768
#define NH 12
#define HD 64
#define M_TOTAL (B_SZ*SEQ)       // 16384
#define QKV_OUT (3*DIM)          // 2304
#define EXP2_SCALE 0.18033688011f   // (1/8) * log2(e)  -- folded into Q at gemm epilogue

typedef _Float16 f16;
typedef __attribute__((ext_vector_type(8))) f16 f16x8;
typedef __attribute__((ext_vector_type(4))) f16 f16x4;
typedef __attribute__((ext_vector_type(2))) __fp16 pk16x2;   // cvt_pkrtz native type
typedef __attribute__((ext_vector_type(4))) short s4_t;
typedef __attribute__((ext_vector_type(4))) float f32x4;
typedef unsigned int u32;
typedef const __attribute__((address_space(1))) u32* gas_t;
typedef __attribute__((address_space(3))) u32* las_t;

union U4 { pk16x2 h2[2]; f16x4 v; };
union U8 { pk16x2 h2[4]; f16x8 v; };
union HS { f16 h; short s; };

__device__ __forceinline__ void async16(const void* g, void* l) {
    __builtin_amdgcn_global_load_lds((gas_t)g, (las_t)l, 16, 0, 0);
}
__device__ __forceinline__ f32x4 mfma32h(f16x8 a, f16x8 b, f32x4 c) {
    return __builtin_amdgcn_mfma_f32_16x16x32_f16(a, b, c, 0, 0, 0);
}
__device__ __forceinline__ f16x8 ldfragh(const short* p) {
    return *(const f16x8*)p;
}

// ---------------- fp32 -> fp16 conversion of x, w_qkv, w_proj ----------------
__global__ void cvt_kernel(const float* __restrict__ x, const float* __restrict__ wq,
                           const float* __restrict__ wp,
                           short* __restrict__ xb, short* __restrict__ wqb, short* __restrict__ wpb) {
    const long nx = (long)M_TOTAL * DIM / 4;
    const long nq = (long)QKV_OUT * DIM / 4;
    const long np = (long)DIM * DIM / 4;
    const long total = nx + nq + np;
    for (long i = (long)blockIdx.x * blockDim.x + threadIdx.x; i < total;
         i += (long)gridDim.x * blockDim.x) {
        const float4* src; short* dst; long off;
        if (i < nx)            { src = (const float4*)x;  dst = xb;  off = i; }
        else if (i < nx + nq)  { src = (const float4*)wq; dst = wqb; off = i - nx; }
        else                   { src = (const float4*)wp; dst = wpb; off = i - nx - nq; }
        float4 v = src[off];
        U4 u;
        u.h2[0] = __builtin_amdgcn_cvt_pkrtz(v.x, v.y);
        u.h2[1] = __builtin_amdgcn_cvt_pkrtz(v.z, v.w);
        *(f16x4*)(dst + off * 4) = u.v;
    }
}

// ---------------- 256x192-tile ONE-phase/tile f16 GEMM:  C = A[M,K] * Bm[N,K]^T -----
// R6 post-mortem: the 4-phase schedule's per-block time (26 us) was ~2x its pipe sum
// (~14 us); the gap was 48 phases x (2 barriers + lgkm/vmcnt latency) of slop.
// This version holds the WHOLE per-wave tile fragment set in registers
// (af[4][2]=32 + bf[6][2]=48 arch VGPR + 96 acc AGPR ~ 206 < 256 two-wave budget)
// so each K-tile is ONE phase: vmcnt(7) -> barrier -> 20 ds_read_b128 ->
// 48-MFMA cluster (24 indep 2-chains) -> barrier -> stage tile t+2 (7 loads) into
// the slot just vacated. 2 barriers + 1 vmcnt per tile (was 8 + 4); A-fragment
// re-read of ph4 eliminated (20 b128/tile vs 24).
// vmcnt: in-flight at loop top is {t, t+1} = 14 loads -> vmcnt(7) = t landed,
// t+1 streaming; vmcnt(0) only on the last tile.
// Grid packing unchanged (gemm<0> 768 = 3 exact CU-rounds; gemm<1> 256 = 1 round).
// Swizzle unchanged (PROVEN zero-conflict: chunk slot = c ^ (row&7), 128B rows,
// both-sides per rule 21). T5 setprio around the MFMA cluster.
// EPI 0: scatter to Q/K [b][h][n][hd] (Q pre-scaled by EXP2_SCALE) and V^T [b][h][hd][n]
// EPI 1: add bias, write fp32 to Cout [M,N]
template<int EPI, int N, int K>
__global__ __launch_bounds__(512, 2) void gemm_bt(const short* __restrict__ A,
                                                  const short* __restrict__ Bm,
                                                  short* __restrict__ Cq, short* __restrict__ Ck,
                                                  short* __restrict__ Cv,
                                                  float* __restrict__ Cout,
                                                  const float* __restrict__ bias) {
    static_assert(K % 128 == 0, "even K-tile count required");
    constexpr int NT = K / 64;       // K-tiles (12)
    constexpr int NIT = NT / 2;      // iterations (2 tiles each)
    constexpr int SLOT = 28672;      // shorts per slot: A 256x64 (16384) + B 192x64 (12288)
    __shared__ short lds[2 * SLOT];  // 114688 B

    const int tid = threadIdx.x;
    const int l = tid & 63, quad = l >> 4, l15 = l & 15, l7 = l15 & 7;
    const int w = tid >> 6, wr = w >> 1, wc = w & 1;   // 4M x 2N wave grid

    // bijective XCD swizzle (nwg % 8 == 0 for both instantiations: 768, 256)
    const int gx = gridDim.x;
    const int nwg = gx * (int)gridDim.y;
    int fid = (int)blockIdx.y * gx + (int)blockIdx.x;
    fid = (fid & 7) * (nwg >> 3) + (fid >> 3);
    const int m0 = (fid / gx) * 256;
    const int n0 = (fid % gx) * 192;

    // staging: unit = 512 threads x 1 load = 64 rows x 8 chunks (16B each).
    const int srow = tid >> 3, sc = tid & 7;
    const int scc = sc ^ (srow & 7);            // (row + u*64)&7 == row&7
    const short* Asrc = A + (size_t)(m0 + srow) * K + scc * 8;
    const short* Bsrc = Bm + (size_t)(n0 + srow) * K + scc * 8;
    const int sdst = tid * 8;

#define STAGE_A(t, u) async16(Asrc + (size_t)((u) * 64) * K + (t) * 64, \
                              &lds[((t) & 1) * SLOT + (u) * 4096 + sdst])
#define STAGE_B(t, u) async16(Bsrc + (size_t)((u) * 64) * K + (t) * 64, \
                              &lds[((t) & 1) * SLOT + 16384 + (u) * 4096 + sdst])

    const int awoff = wr * 4096 + l15 * 64;            // A row = wr*64 + rt*16 + l15
    const int bwoff = 16384 + wc * 6144 + l15 * 64;    // B row = wc*96 + ct*16 + l15
    const int c0 = (quad ^ l7) * 8;
    const int c1 = ((4 + quad) ^ l7) * 8;

#define RD_ALL(SB) do {                                                                        \
        const int ab_ = (SB) + awoff;                                                          \
        af[0][0] = ldfragh(&lds[ab_ + c0]);        af[0][1] = ldfragh(&lds[ab_ + c1]);         \
        af[1][0] = ldfragh(&lds[ab_ + 1024 + c0]); af[1][1] = ldfragh(&lds[ab_ + 1024 + c1]);  \
        af[2][0] = ldfragh(&lds[ab_ + 2048 + c0]); af[2][1] = ldfragh(&lds[ab_ + 2048 + c1]);  \
        af[3][0] = ldfragh(&lds[ab_ + 3072 + c0]); af[3][1] = ldfragh(&lds[ab_ + 3072 + c1]);  \
        const int bb_ = (SB) + bwoff;                                                          \
        bf[0][0] = ldfragh(&lds[bb_ + c0]);        bf[0][1] = ldfragh(&lds[bb_ + c1]);         \
        bf[1][0] = ldfragh(&lds[bb_ + 1024 + c0]); bf[1][1] = ldfragh(&lds[bb_ + 1024 + c1]);  \
        bf[2][0] = ldfragh(&lds[bb_ + 2048 + c0]); bf[2][1] = ldfragh(&lds[bb_ + 2048 + c1]);  \
        bf[3][0] = ldfragh(&lds[bb_ + 3072 + c0]); bf[3][1] = ldfragh(&lds[bb_ + 3072 + c1]);  \
        bf[4][0] = ldfragh(&lds[bb_ + 4096 + c0]); bf[4][1] = ldfragh(&lds[bb_ + 4096 + c1]);  \
        bf[5][0] = ldfragh(&lds[bb_ + 5120 + c0]); bf[5][1] = ldfragh(&lds[bb_ + 5120 + c1]);  \
    } while (0)

#define BAR2() do { __builtin_amdgcn_s_barrier(); __builtin_amdgcn_sched_barrier(0); } while (0)
#define VMC7() asm volatile("s_waitcnt vmcnt(7)" ::: "memory")
#define VMC0() asm volatile("s_waitcnt vmcnt(0)" ::: "memory")

#define MFMA_ALL() do {                                        \
        _Pragma("unroll")                                      \
        for (int rt = 0; rt < 4; ++rt)                         \
            _Pragma("unroll")                                  \
            for (int ct = 0; ct < 6; ++ct) {                   \
                f32x4 tacc = acc[rt][ct];                      \
                tacc = mfma32h(af[rt][0], bf[ct][0], tacc);    \
                tacc = mfma32h(af[rt][1], bf[ct][1], tacc);    \
                acc[rt][ct] = tacc;                            \
            }                                                  \
    } while (0)

#define TILE_BODY(t, SB) do {                                                  \
        if ((t) < NT - 1) VMC7(); else VMC0();                                 \
        BAR2();                                                                \
        RD_ALL(SB);                                                            \
        __builtin_amdgcn_s_setprio(1);                                         \
        MFMA_ALL();                                                            \
        __builtin_amdgcn_s_setprio(0);                                         \
        BAR2();                                                                \
        if ((t) + 2 < NT) {                                                    \
            STAGE_A((t) + 2, 0); STAGE_A((t) + 2, 1);                          \
            STAGE_A((t) + 2, 2); STAGE_A((t) + 2, 3);                          \
            STAGE_B((t) + 2, 0); STAGE_B((t) + 2, 1); STAGE_B((t) + 2, 2);     \
        }                                                                      \
    } while (0)

    f32x4 acc[4][6];
#pragma unroll
    for (int i = 0; i < 4; ++i)
#pragma unroll
        for (int j = 0; j < 6; ++j) acc[i][j] = (f32x4){0.f, 0.f, 0.f, 0.f};
    f16x8 af[4][2], bf[6][2];

    // prologue: tiles 0 and 1 fully staged (14 loads in flight)
    STAGE_A(0, 0); STAGE_A(0, 1); STAGE_A(0, 2); STAGE_A(0, 3);
    STAGE_B(0, 0); STAGE_B(0, 1); STAGE_B(0, 2);
    STAGE_A(1, 0); STAGE_A(1, 1); STAGE_A(1, 2); STAGE_A(1, 3);
    STAGE_B(1, 0); STAGE_B(1, 1); STAGE_B(1, 2);

#pragma unroll 1
    for (int i = 0; i < NIT; ++i) {
        TILE_BODY(2 * i, 0);
        TILE_BODY(2 * i + 1, SLOT);
    }
#undef STAGE_A
#undef STAGE_B
#undef RD_ALL
#undef MFMA_ALL
#undef TILE_BODY

    // epilogue: acc[rt][ct] covers row rt*16, col ct*16 of the wave's 64x96 tile
#pragma unroll
    for (int rt = 0; rt < 4; ++rt) {
        const int mrow = m0 + wr * 64 + rt * 16 + quad * 4;
#pragma unroll
        for (int ct = 0; ct < 6; ++ct) {
            const int col = n0 + wc * 96 + ct * 16 + l15;
            if (EPI == 0) {
                int s = col / DIM;
                int h = (col - s * DIM) >> 6, hd = col & 63;
                int b = mrow >> 10, nn = mrow & 1023;
                if (s == 2) {
                    // V transposed: [b][h][hd][n]; 4 consecutive n -> one 8B store
                    U4 u;
                    u.h2[0] = __builtin_amdgcn_cvt_pkrtz(acc[rt][ct][0], acc[rt][ct][1]);
                    u.h2[1] = __builtin_amdgcn_cvt_pkrtz(acc[rt][ct][2], acc[rt][ct][3]);
                    *(f16x4*)&Cv[(((size_t)b * NH + h) * HD + hd) * SEQ + nn] = u.v;
                } else {
                    short* dst = (s == 0) ? Cq : Ck;
                    const float qs = (s == 0) ? EXP2_SCALE : 1.0f;
#pragma unroll
                    for (int r = 0; r < 4; ++r) {
                        HS t; t.h = (f16)(acc[rt][ct][r] * qs);
                        dst[(((size_t)b * NH + h) * SEQ + nn + r) * HD + hd] = t.s;
                    }
                }
            } else {
                float bv = bias[col];
#pragma unroll
                for (int r = 0; r < 4; ++r)
                    Cout[(size_t)(mrow + r) * N + col] = acc[rt][ct][r] + bv;
            }
        }
    }
}

// ---------------- attention: LDS-staged flash, KVBLK=64, 3-buffer pipeline ----------
// (unchanged from round 6 -- plain launch_bounds, no spill, < 77 us)
__global__ __launch_bounds__(256) void attn_kernel(const short* __restrict__ Q,
                                                   const short* __restrict__ Km,
                                                   const short* __restrict__ Vt,
                                                   short* __restrict__ O) {
    __shared__ short lds[3][8192];   // per buffer: K[2 half][32x64] | V^T[2 half][64x32]
    const int tid = threadIdx.x;
    const int w = tid >> 6, l = tid & 63, quad = l >> 4, l15 = l & 15;
    const int bid = blockIdx.x;
    const int xcd = bid & 7, kk = bid >> 3;
    const int head = xcd + 8 * (kk >> 2);        // 0..191, 4 q-chunks/head per XCD
    const int q0 = (kk & 3) * 256 + w * 64;      // this wave's 64 q rows
    const int b = head / NH, h = head - b * NH;
    const short* Qp = Q + (size_t)head * (SEQ * HD);
    const short* Kp = Km + (size_t)head * (SEQ * HD);
    const short* Vp = Vt + (size_t)head * (SEQ * HD);   // [hd][n]

    // Q as B-operand fragments: B[n=q=l15][k=hd=quad*8+j]; EXP2_SCALE pre-folded.
    f16x8 qf[4][2];
#pragma unroll
    for (int qt = 0; qt < 4; ++qt)
#pragma unroll
        for (int hf = 0; hf < 2; ++hf)
            qf[qt][hf] = *(const f16x8*)&Qp[(q0 + qt * 16 + l15) * HD + hf * 32 + quad * 8];

    f32x4 oacc[4][4];
#pragma unroll
    for (int qt = 0; qt < 4; ++qt)
#pragma unroll
        for (int ht = 0; ht < 4; ++ht) oacc[qt][ht] = (f32x4){0.f, 0.f, 0.f, 0.f};
    float psum[4] = {0.f, 0.f, 0.f, 0.f};

    // staging: 4 x 16B per thread per 64-kv block (2 K-halves + 2 V-halves)
    const int kr = tid >> 3, kc = tid & 7;
    const int kcc = kc ^ ((kr & 3) ^ (((kr >> 3) & 3) << 1));
    const short* kSrc = Kp + kr * HD + kcc * 8;     // + (g*64 + u*32)*HD per block
    const int kDst = kr * 64 + kc * 8;              // + u*2048
    const int vr = tid >> 2, vc = tid & 3;
    const int vcc = vc ^ ((vr >> 1) & 3);
    const short* vSrc = Vp + vr * SEQ + vcc * 8;    // + g*64 + hf*32 per block
    const int vDst = 4096 + vr * 32 + vc * 8;       // + hf*2048

#define STAGE(bf, g) do {                                            \
        async16(kSrc + (size_t)(g) * 64 * HD, &lds[bf][kDst]);       \
        async16(kSrc + (size_t)((g) * 64 + 32) * HD,                 \
                &lds[bf][kDst + 2048]);                              \
        async16(vSrc + (g) * 64, &lds[bf][vDst]);                    \
        async16(vSrc + (g) * 64 + 32, &lds[bf][vDst + 2048]);       \
    } while (0)

    const int rA = 8 * (l15 >> 2) + (l15 & 3);
    const int sk = (l15 & 3) ^ ((l15 >> 2) << 1);
    const int offK = rA * 64 + ((quad ^ sk) * 8);                        // + half*2048
    const int offV = 4096 + l15 * 32 + ((quad ^ ((l15 >> 1) & 3)) * 8);  // + half*2048

    STAGE(0, 0); STAGE(1, 1);   // 2-deep prologue (8 loads in flight)

    int cur = 0, nb = 2;        // cur = g%3, nb = (g+2)%3, tracked incrementally
    for (int g = 0; g < 16; ++g) {
        if (g <= 14) asm volatile("s_waitcnt vmcnt(4)" ::: "memory");
        else         asm volatile("s_waitcnt vmcnt(0)" ::: "memory");
        __builtin_amdgcn_s_barrier();
        // buf nb was last read at iter g-1; all waves crossed the barrier after
        // consuming their ds_reads of it -> safe to overwrite.
        if (g < 14) STAGE(nb, g + 2);

        const short* bufp = &lds[cur][0];
#pragma unroll
        for (int half = 0; half < 2; ++half) {
            const short* kb = bufp + half * 2048;
            f16x8 kA0 = ldfragh(kb + offK);
            f16x8 kA1 = ldfragh(kb + (offK ^ 32));
            f16x8 kB0 = ldfragh(kb + offK + 256);
            f16x8 kB1 = ldfragh(kb + (offK ^ 32) + 256);
            f16x8 v0 = ldfragh(kb + offV);
            f16x8 v1 = ldfragh(kb + offV + 512);
            f16x8 v2 = ldfragh(kb + offV + 1024);
            f16x8 v3 = ldfragh(kb + offV + 1536);

            __builtin_amdgcn_s_setprio(1);
#pragma unroll
            for (int qt = 0; qt < 4; ++qt) {
                f32x4 sA = (f32x4){0.f, 0.f, 0.f, 0.f};
                sA = mfma32h(kA0, qf[qt][0], sA);
                sA = mfma32h(kA1, qf[qt][1], sA);
                f32x4 sB = (f32x4){0.f, 0.f, 0.f, 0.f};
                sB = mfma32h(kB0, qf[qt][0], sB);
                sB = mfma32h(kB1, qf[qt][1], sB);
                float eA0 = __builtin_amdgcn_exp2f(sA[0]);
                float eA1 = __builtin_amdgcn_exp2f(sA[1]);
                float eA2 = __builtin_amdgcn_exp2f(sA[2]);
                float eA3 = __builtin_amdgcn_exp2f(sA[3]);
                float eB0 = __builtin_amdgcn_exp2f(sB[0]);
                float eB1 = __builtin_amdgcn_exp2f(sB[1]);
                float eB2 = __builtin_amdgcn_exp2f(sB[2]);
                float eB3 = __builtin_amdgcn_exp2f(sB[3]);
                psum[qt] += ((eA0 + eA1) + (eA2 + eA3)) + ((eB0 + eB1) + (eB2 + eB3));
                U8 u;
                u.h2[0] = __builtin_amdgcn_cvt_pkrtz(eA0, eA1);
                u.h2[1] = __builtin_amdgcn_cvt_pkrtz(eA2, eA3);
                u.h2[2] = __builtin_amdgcn_cvt_pkrtz(eB0, eB1);
                u.h2[3] = __builtin_amdgcn_cvt_pkrtz(eB2, eB3);
                oacc[qt][0] = mfma32h(v0, u.v, oacc[qt][0]);
                oacc[qt][1] = mfma32h(v1, u.v, oacc[qt][1]);
                oacc[qt][2] = mfma32h(v2, u.v, oacc[qt][2]);
                oacc[qt][3] = mfma32h(v3, u.v, oacc[qt][3]);
            }
            __builtin_amdgcn_s_setprio(0);
        }
        cur = (cur == 2) ? 0 : cur + 1;
        nb = (nb == 2) ? 0 : nb + 1;
    }
#undef STAGE

    // full row sums: reduce partials across the 4 quads (lanes differing in bits 4,5)
#pragma unroll
    for (int qt = 0; qt < 4; ++qt) {
        psum[qt] += __shfl_xor(psum[qt], 16);
        psum[qt] += __shfl_xor(psum[qt], 32);
    }

    // epilogue: lane holds O[q=l15][hd=ht*16+quad*4+r] -> four 8B stores per q-tile
#pragma unroll
    for (int qt = 0; qt < 4; ++qt) {
        float rinv = 1.0f / psum[qt];
        short* orow = &O[((size_t)b * SEQ + q0 + qt * 16 + l15) * DIM + h * HD + quad * 4];
#pragma unroll
        for (int ht = 0; ht < 4; ++ht) {
            U4 u;
            u.h2[0] = __builtin_amdgcn_cvt_pkrtz(oacc[qt][ht][0] * rinv, oacc[qt][ht][1] * rinv);
            u.h2[1] = __builtin_amdgcn_cvt_pkrtz(oacc[qt][ht][2] * rinv, oacc[qt][ht][3] * rinv);
            *(f16x4*)(orow + ht * 16) = u.v;
        }
    }
}

extern "C" void kernel_launch(void* const* d_in, const int* in_sizes, int n_in,
                              void* d_out, int out_size, void* d_ws, size_t ws_size,
                              hipStream_t stream) {
    const float* x      = (const float*)d_in[0];
    const float* w_qkv  = (const float*)d_in[1];
    const float* w_proj = (const float*)d_in[2];
    const float* b_proj = (const float*)d_in[3];
    float* out = (float*)d_out;

    short* p = (short*)d_ws;
    short* Xb  = p; p += (size_t)M_TOTAL * DIM;
    short* Wqb = p; p += (size_t)QKV_OUT * DIM;
    short* Wpb = p; p += (size_t)DIM * DIM;
    short* Qb  = p; p += (size_t)B_SZ * NH * SEQ * HD;
    short* Kb  = p; p += (size_t)B_SZ * NH * SEQ * HD;
    short* Vtb = p; p += (size_t)B_SZ * NH * SEQ * HD;   // transposed [b][h][hd][n]
    short* Ob  = p; p += (size_t)M_TOTAL * DIM;

    cvt_kernel<<<1024, 256, 0, stream>>>(x, w_qkv, w_proj, Xb, Wqb, Wpb);
    gemm_bt<0, QKV_OUT, DIM><<<dim3(QKV_OUT / 192, M_TOTAL / 256), 512, 0, stream>>>(
        Xb, Wqb, Qb, Kb, Vtb, nullptr, nullptr);
    attn_kernel<<<B_SZ * NH * (SEQ / 256), 256, 0, stream>>>(Qb, Kb, Vtb, Ob);
    gemm_bt<1, DIM, DIM><<<dim3(DIM / 192, M_TOTAL / 256), 512, 0, stream>>>(
        Ob, Wpb, nullptr, nullptr, nullptr, out, b_proj);
}